// Round 14
// baseline (70.497 us; speedup 1.0000x reference)
//
#include <hip/hip_runtime.h>
#include <hip/hip_bf16.h>

// AttentionBlock B=4, C=128, N=4096.
// gn_wconv (partial stats + w->bf16)
// -> qkv_fused (GN finalize+apply + MFMA QKV; LDS-restaged coalesced stores)
// -> flash_attn (32x32x16 MFMA, register-resident P. r14 = r5 + dual-s QK
//                ILP split: each jt's 8-deep dependent MFMA chain becomes two
//                4-deep chains over even/odd kc (s_a init -SMAX, s_b init 0,
//                summed into exp2's argument). +16 TRANSIENT regs inside QK
//                only (r5's peak is in PV) -- no held-across-barrier state,
//                unlike r12's spill. All else r5-verbatim: staggered prefetch,
//                sequential jt, dbuf K/V, ONE barrier/chunk, 108 VGPR base.)
// -> merge_out (sum 4 partials * 1/l + MFMA out-proj + bias + residual)

#define CH 128
#define SEQ 4096
#define EPSV 1e-5f
// 1/sqrt(128) * log2(e): softmax runs in base-2 domain
#define QSCALE (0.08838834764831845f * 1.4426950408889634f)
// fixed softmax shift: base-2 logits bounded |s2| <~ 15; exp2 only overflows
// at s2-M > 127 -> enormous margin. Same M for all j-splits makes merge
// factors collapse to 1/sum(l).
#define SMAX 24.0f

typedef unsigned short u16;
typedef unsigned int u32;
typedef __attribute__((ext_vector_type(8))) short short8;    // 8 bf16 (4 VGPRs)
typedef __attribute__((ext_vector_type(4))) u32 u32x4;
typedef __attribute__((ext_vector_type(4))) float floatx4;   // 16x16 MFMA C/D
typedef __attribute__((ext_vector_type(16))) float floatx16; // 32x32 MFMA C/D

__device__ __forceinline__ float bf2f(u16 h) {
    return __uint_as_float(((u32)h) << 16);
}
__device__ __forceinline__ float lo16(u32 wd) { return __uint_as_float(wd << 16); }
__device__ __forceinline__ float hi16(u32 wd) { return __uint_as_float(wd & 0xffff0000u); }
__device__ __forceinline__ u16 f2bf(float f) {
    u32 u = __float_as_uint(f);
    return (u16)((u + 0x7fffu + ((u >> 16) & 1u)) >> 16);
}
__device__ __forceinline__ u32 pkbf(float a, float b) {   // packed RNE cvt (low=a)
    __hip_bfloat162 h = __float22bfloat162_rn(make_float2(a, b));
    u32 r;
    __builtin_memcpy(&r, &h, 4);   // folds to SSA extract; no alloca
    return r;
}
__device__ __forceinline__ floatx4 mfma16(short8 a, short8 b, floatx4 c) {
    return __builtin_amdgcn_mfma_f32_16x16x32_bf16(a, b, c, 0, 0, 0);
}
__device__ __forceinline__ floatx16 mfma32(short8 a, short8 b, floatx16 c) {
    return __builtin_amdgcn_mfma_f32_32x32x16_bf16(a, b, c, 0, 0, 0);
}
// v_permlane32_swap_b32: a' = [a.lo32, b.lo32], b' = [a.hi32, b.hi32]
// non-volatile: pure lane shuffle, let the scheduler move it freely
__device__ __forceinline__ void pl32(u32& a, u32& b) {
    asm("v_permlane32_swap_b32 %0, %1" : "+v"(a), "+v"(b));
}
__device__ __forceinline__ short8 mk8(u32 a, u32 b, u32 c, u32 d) {
    u32x4 v = (u32x4){a, b, c, d};                        // SSA vector literal
    return __builtin_bit_cast(short8, v);                 // ext_vec -> ext_vec ok
}

// ---------------- Kernel 1: GN partial stats + weight conversion ---------------
// 512 blocks: 0..255 stats (bg,sub), 256..511 weight bf16 convert.
__global__ void gn_wconv(const float* __restrict__ x, float* __restrict__ part,
                         const float* __restrict__ w_qkv, const float* __restrict__ w_out,
                         u16* __restrict__ wq, u16* __restrict__ wo) {
    if (blockIdx.x >= 256) {
        int i = (blockIdx.x - 256) * 256 + threadIdx.x;   // 65536 total
        if (i < 49152) wq[i] = f2bf(w_qkv[i]);
        else           wo[i - 49152] = f2bf(w_out[i - 49152]);
        return;
    }
    int bg = blockIdx.x >> 3, sub = blockIdx.x & 7;
    const float4* xp = (const float4*)(x + (size_t)bg * 65536 + sub * 8192);
    float s = 0.f, sq = 0.f;
    for (int r = 0; r < 8; ++r) {
        float4 v = xp[threadIdx.x + 256 * r];
        s  += v.x + v.y + v.z + v.w;
        sq += v.x*v.x + v.y*v.y + v.z*v.z + v.w*v.w;
    }
    for (int off = 32; off; off >>= 1) {
        s  += __shfl_down(s, off, 64);
        sq += __shfl_down(sq, off, 64);
    }
    __shared__ float ls[8];
    int wave = threadIdx.x >> 6, lane = threadIdx.x & 63;
    if (lane == 0) { ls[wave*2] = s; ls[wave*2+1] = sq; }
    __syncthreads();
    if (threadIdx.x == 0) {
        float ts = 0.f, tq = 0.f;
        for (int w = 0; w < 4; ++w) { ts += ls[w*2]; tq += ls[w*2+1]; }
        part[blockIdx.x * 2]     = ts;
        part[blockIdx.x * 2 + 1] = tq;
    }
}

// ---------------- Kernel 2: fused GN-apply + MFMA QKV projection ---------------
// 512 blocks = (b, 32-pos chunk). hT[32n][136c] in LDS; wave owns 6 o-tiles.
// Epilogue: C tiles -> LDS stage buffers -> fully-coalesced uint4 stores.
__global__ __launch_bounds__(256, 2) void qkv_fused(
        const float* __restrict__ x, const float* __restrict__ gw,
        const float* __restrict__ gb, const float* __restrict__ part,
        const u16* __restrict__ wq, const float* __restrict__ b_qkv,
        u16* __restrict__ qT, u16* __restrict__ kT, u16* __restrict__ v) {
    __shared__ __align__(16) u16 hT[32 * 136];     // input stage
    __shared__ __align__(16) u16 qbuf[32 * 132];   // [n][c] padded
    __shared__ __align__(16) u16 kbuf[32 * 132];
    __shared__ __align__(16) u16 vbuf[128 * 36];   // [c][n] padded
    __shared__ float cw[128], cb[128];
    int bx = blockIdx.x;            // 512
    int nc = bx & 127, b = bx >> 7;
    int n0 = nc * 32;
    int t = threadIdx.x, w = t >> 6, lane = t & 63;
    int quad = lane >> 4, l15 = lane & 15;

    // finalize GN stats -> per-channel scale/bias
    if (t < 128) {
        int g = t >> 4;
        float s = 0.f, sq = 0.f;
        #pragma unroll
        for (int u = 0; u < 8; ++u) {
            s  += part[((b * 8 + g) * 8 + u) * 2];
            sq += part[((b * 8 + g) * 8 + u) * 2 + 1];
        }
        float mean = s / 65536.f;
        float rstd = rsqrtf(sq / 65536.f - mean * mean + EPSV);
        float wgt = gw[t] * rstd;
        cw[t] = wgt;
        cb[t] = gb[t] - mean * wgt;
    }

    // weight fragments: wave w -> o-tiles w*6 .. w*6+5
    short8 wf[6][4];
    float bqk[6];
    #pragma unroll
    for (int j = 0; j < 6; ++j) {
        int orow = (w * 6 + j) * 16 + l15;
        #pragma unroll
        for (int kt = 0; kt < 4; ++kt)
            wf[j][kt] = *(const short8*)(wq + orow * 128 + kt * 32 + quad * 8);
        bqk[j] = b_qkv[orow];
    }
    __syncthreads();

    // stage GN'd x transposed (32 pos x 128 c)
    #pragma unroll
    for (int r = 0; r < 4; ++r) {
        int u = r * 256 + t;
        int c = u >> 3, col = (u & 7) * 4;
        float wgt = cw[c], bs = cb[c];
        float4 xv = *(const float4*)(x + ((size_t)(b * 128 + c)) * SEQ + n0 + col);
        hT[(col + 0) * 136 + c] = f2bf(fmaf(xv.x, wgt, bs));
        hT[(col + 1) * 136 + c] = f2bf(fmaf(xv.y, wgt, bs));
        hT[(col + 2) * 136 + c] = f2bf(fmaf(xv.z, wgt, bs));
        hT[(col + 3) * 136 + c] = f2bf(fmaf(xv.w, wgt, bs));
    }
    __syncthreads();

    #pragma unroll
    for (int nt = 0; nt < 2; ++nt) {
        short8 hf[4];
        #pragma unroll
        for (int kt = 0; kt < 4; ++kt)
            hf[kt] = *(const short8*)(hT + (nt * 16 + l15) * 136 + kt * 32 + quad * 8);
        floatx4 acc[6];
        #pragma unroll
        for (int j = 0; j < 6; ++j) acc[j] = (floatx4)0.f;
        #pragma unroll
        for (int kt = 0; kt < 4; ++kt)
            #pragma unroll
            for (int j = 0; j < 6; ++j) {
                if (w * 6 + j < 16) acc[j] = mfma16(hf[kt], wf[j][kt], acc[j]);
                else                acc[j] = mfma16(wf[j][kt], hf[kt], acc[j]);
            }
        // scatter C tiles into LDS stage buffers
        #pragma unroll
        for (int j = 0; j < 6; ++j) {
            int T = w * 6 + j;
            if (T < 8) {            // q: C[pos][o] -> qbuf[n][c]
                int o = T * 16 + l15;
                #pragma unroll
                for (int r = 0; r < 4; ++r)
                    qbuf[(nt * 16 + quad * 4 + r) * 132 + o] =
                        f2bf((acc[j][r] + bqk[j]) * QSCALE);
            } else if (T < 16) {    // k -> kbuf[n][c]
                int o = (T - 8) * 16 + l15;
                #pragma unroll
                for (int r = 0; r < 4; ++r)
                    kbuf[(nt * 16 + quad * 4 + r) * 132 + o] =
                        f2bf(acc[j][r] + bqk[j]);
            } else {                // v: C[o][pos] -> vbuf[c][n]
                #pragma unroll
                for (int r = 0; r < 4; ++r) {
                    int ov = (T - 16) * 16 + quad * 4 + r;
                    vbuf[ov * 36 + nt * 16 + l15] = f2bf(acc[j][r] + b_qkv[256 + ov]);
                }
            }
        }
    }
    __syncthreads();

    // cooperative coalesced stores
    {   // q,k: [32n][128c] -> contiguous 4096-elem global region each
        u16* qg = qT + ((size_t)b * SEQ + n0) * CH;
        u16* kg = kT + ((size_t)b * SEQ + n0) * CH;
        #pragma unroll
        for (int rep = 0; rep < 2; ++rep) {
            int idx = rep * 256 + t;
            int n = idx >> 4, c8 = (idx & 15) * 8;
            *(uint4*)(qg + n * CH + c8) = *(const uint4*)(qbuf + n * 132 + c8);
            *(uint4*)(kg + n * CH + c8) = *(const uint4*)(kbuf + n * 132 + c8);
        }
        // v: [128c][32n] -> per-c rows of 64 B
        #pragma unroll
        for (int rep = 0; rep < 2; ++rep) {
            int idx = rep * 256 + t;
            int c = idx >> 2, n8 = (idx & 3) * 8;
            *(uint4*)(v + ((size_t)(b * CH + c)) * SEQ + n0 + n8) =
                *(const uint4*)(vbuf + c * 36 + n8);
        }
    }
}

// ---------------- Kernel 3: MFMA flash attention (32x32, register P) -----------
// 512 blocks = (b, iblk of 128 i, js of 4); 16 chunks of 64 j per split.
// js-fastest ordering (per-XCD WS fits L2). 4 waves x 32-i tiles.
// S^T (A=K, B=Q) via 32x32x16 MFMA; SMAX folded into acc init; P -> PV
// B-frags fully in-register (cvt_pk + permlane32_swap).
// Staggered prefetch (spill control): K(ch+1) issued at loop top (held
// 16 VGPRs); V(ch+1) issued after softmax (transient); both ds-written at
// iter end. Sequential jt tiles; r14: per-jt QK uses TWO 4-deep chains
// (s_a even kc / s_b odd kc) to halve dependent-MFMA latency; summed into
// exp2's argument. Double-buffered K/V (71680 B LDS), ONE barrier per chunk.
__global__ __launch_bounds__(256, 2) void flash_attn(
        const u16* __restrict__ qT, const u16* __restrict__ kT,
        const u16* __restrict__ v, u16* __restrict__ partO,
        float* __restrict__ lbuf) {
    __shared__ __align__(16) char smem[71680];
    // buffer p (p=0,1): kts = smem + p*35840 [64 j][136 c] (17408 B),
    //                   vts = kts + 17408   [128 c][72 j]  (18432 B)
    u16* qts = (u16*)(smem + 35840);   // [128 i][136 c] aliases buffer 1 (init)
    u16* lds2 = (u16*)smem;            // [128 i][132 c] epilogue restage (buf 0)

    int bx = blockIdx.x;               // js fastest -> L2/XCD locality
    int js = bx & 3, iblk = (bx >> 2) & 31, b = bx >> 7;
    int t = threadIdx.x, w = t >> 6, lane = t & 63;
    int il = lane & 31, h = lane >> 5;
    int i0 = iblk * 128, j0 = js * 1024;

    // per-thread staging coordinates
    int tj = t >> 4, tc8 = (t & 15) * 8;    // K: j = r*16+tj, c-offset tc8
    int tv = t >> 3, vc8 = (t & 7) * 8;     // V: c = r*32+tv, j-offset vc8

    // ---- stage Q tile ([n][c]) into buffer-1 region, read 32x32 B-frags ----
    {
        const u16* qb = qT + ((size_t)b * SEQ + i0) * CH;
        for (int r = 0; r < 8; ++r) {
            int u = r * 256 + t;
            int i = u >> 4, c16 = u & 15;
            *(uint4*)(qts + i * 136 + c16 * 8) =
                *(const uint4*)(qb + (size_t)i * CH + c16 * 8);
        }
    }
    __syncthreads();
    short8 qf[8];   // B[k=c][n=i]: lane holds Q[i = w*32+il][c = kc*16 + 8h + e]
    #pragma unroll
    for (int kc = 0; kc < 8; ++kc)
        qf[kc] = *(const short8*)(qts + (w * 32 + il) * 136 + kc * 16 + h * 8);
    // qts (buffer 1) is first overwritten by the ds_write at the END of iter 0
    // (staging chunk 1), which is past the prologue barrier below -> all waves'
    // qf ds_reads complete (own-wave lgkmcnt + barrier ordering) before that.

    const u16* kTb = kT + ((size_t)b * SEQ + j0) * CH;
    const u16* vb  = v  + (size_t)b * CH * SEQ + j0;

    // ---- prologue: stage chunk 0 into buffer 0 (transient regs) ----
    {
        u16* kts0 = (u16*)smem;
        u16* vts0 = kts0 + 8704;
        #pragma unroll
        for (int r = 0; r < 4; ++r)
            *(uint4*)(kts0 + (r * 16 + tj) * 136 + tc8) =
                *(const uint4*)(kTb + (size_t)(r * 16 + tj) * CH + tc8);
        #pragma unroll
        for (int r = 0; r < 4; ++r)
            *(uint4*)(vts0 + (r * 32 + tv) * 72 + vc8) =
                *(const uint4*)(vb + (size_t)(r * 32 + tv) * SEQ + vc8);
    }
    __syncthreads();

    float l_part = 0.f;
    floatx16 o[4];   // O^T[c = ct*32+row][i = il]
    #pragma unroll
    for (int ct = 0; ct < 4; ++ct) o[ct] = (floatx16)0.f;

    for (int ch = 0; ch < 16; ++ch) {
        u16* kts = (u16*)(smem + (ch & 1) * 35840);
        u16* vts = kts + 8704;   // +17408 B
        u16* ktsN = (u16*)(smem + ((ch + 1) & 1) * 35840);
        u16* vtsN = ktsN + 8704;
        int jb1 = (ch + 1) * 64;
        bool pf = (ch < 15);

        // K(ch+1) global loads: issued first, consumed at iter end (ds_write).
        // Latency hidden under the entire chunk body.
        uint4 kreg[4];
        if (pf) {
            #pragma unroll
            for (int r = 0; r < 4; ++r)
                kreg[r] = *(const uint4*)(kTb + (size_t)(jb1 + r * 16 + tj) * CH + tc8);
        }

        // ---- QK + softmax + pack, one 32-j tile at a time (reg pressure) ----
        // S^T tile: row j_loc = jt*32 + (r&3)+8*(r>>2)+4h, col i = il.
        // Dual 4-deep chains: s_a (even kc, init -SMAX) + s_b (odd kc, init 0)
        // -> scores come out pre-shifted after the 16-add merge.
        short8 pfr[4];   // PV B-frags: j 0..15 / 16..31 / 32..47 / 48..63
        #pragma unroll
        for (int jt = 0; jt < 2; ++jt) {
            floatx16 sa = (floatx16)(-SMAX);
            floatx16 sb = (floatx16)0.f;
            #pragma unroll
            for (int kc = 0; kc < 8; kc += 2) {
                short8 kfa = *(const short8*)(kts + (jt * 32 + il) * 136 + kc * 16 + h * 8);
                short8 kfb = *(const short8*)(kts + (jt * 32 + il) * 136 + (kc + 1) * 16 + h * 8);
                sa = mfma32(kfa, qf[kc], sa);
                sb = mfma32(kfb, qf[kc + 1], sb);
            }
            float p[16];
            #pragma unroll
            for (int r = 0; r < 16; ++r)
                p[r] = __builtin_amdgcn_exp2f(sa[r] + sb[r]);
            l_part += ((((p[0]+p[1])+(p[2]+p[3])) + ((p[4]+p[5])+(p[6]+p[7])))
                    +  (((p[8]+p[9])+(p[10]+p[11])) + ((p[12]+p[13])+(p[14]+p[15]))));
            u32 a0 = pkbf(p[0],  p[1]),  a1 = pkbf(p[2],  p[3]);
            u32 a2 = pkbf(p[4],  p[5]),  a3 = pkbf(p[6],  p[7]);
            u32 b0 = pkbf(p[8],  p[9]),  b1 = pkbf(p[10], p[11]);
            u32 b2 = pkbf(p[12], p[13]), b3 = pkbf(p[14], p[15]);
            pl32(a0, a2); pl32(a1, a3);
            pl32(b0, b2); pl32(b1, b3);
            pfr[2 * jt]     = mk8(a0, a1, a2, a3);
            pfr[2 * jt + 1] = mk8(b0, b1, b2, b3);
        }

        // V(ch+1) global loads: issued after softmax, consumed at iter end.
        // Latency hidden under PV. Transient 16 VGPRs.
        uint4 vreg[4];
        if (pf) {
            #pragma unroll
            for (int r = 0; r < 4; ++r)
                vreg[r] = *(const uint4*)(vb + (size_t)(r * 32 + tv) * SEQ + jb1 + vc8);
        }

        // ---- PV: O^T[c][i] += V[c][j] * P[i][j]^T; 4 indep chains ----
        __builtin_amdgcn_s_setprio(1);
        #pragma unroll
        for (int ct = 0; ct < 4; ++ct) {
            const u16* vrow = vts + (ct * 32 + il) * 72;
            short8 vf0 = *(const short8*)(vrow + h * 8);
            short8 vf1 = *(const short8*)(vrow + 16 + h * 8);
            short8 vf2 = *(const short8*)(vrow + 32 + h * 8);
            short8 vf3 = *(const short8*)(vrow + 48 + h * 8);
            o[ct] = mfma32(vf0, pfr[0], o[ct]);
            o[ct] = mfma32(vf1, pfr[1], o[ct]);
            o[ct] = mfma32(vf2, pfr[2], o[ct]);
            o[ct] = mfma32(vf3, pfr[3], o[ct]);
        }
        __builtin_amdgcn_s_setprio(0);

        // ---- write chunk ch+1 into the other buffer, single barrier ----
        // Safe: all waves passed barrier(ch), so every wave's reads of
        // buf[(ch+1)&1] (done during iter ch-1) are complete.
        if (pf) {
            #pragma unroll
            for (int r = 0; r < 4; ++r)
                *(uint4*)(ktsN + (r * 16 + tj) * 136 + tc8) = kreg[r];
            #pragma unroll
            for (int r = 0; r < 4; ++r)
                *(uint4*)(vtsN + (r * 32 + tv) * 72 + vc8) = vreg[r];
        }
        __syncthreads();
    }

    // ---- epilogue: O tiles -> LDS restage -> fully-coalesced stores ----
    // C layout: col i = il (wave rows w*32+il), row c = ct*32 + (r&3)+8*(r>>2)+4h.
    // lds2 sits in buffer 0: chunk-14 reads of buffer 0 completed before the
    // final barrier at the end of iter 15, so writing here is race-free.
    #pragma unroll
    for (int ct = 0; ct < 4; ++ct)
        #pragma unroll
        for (int g = 0; g < 4; ++g) {
            uint2 pk2 = make_uint2(pkbf(o[ct][4*g+0], o[ct][4*g+1]),
                                   pkbf(o[ct][4*g+2], o[ct][4*g+3]));
            *(uint2*)(lds2 + (w * 32 + il) * 132 + ct * 32 + 8 * g + 4 * h) = pk2;
        }
    __syncthreads();
    int bi = b * 32 + iblk;
    u16* pb = partO + ((size_t)(js * 128 + bi)) * 16384;   // [128 i][128 c]
    #pragma unroll
    for (int rep = 0; rep < 8; ++rep) {
        int idx = rep * 256 + t;
        int i = idx >> 4, c8 = (idx & 15) * 8;
        *(uint4*)(pb + i * 128 + c8) = *(const uint4*)(lds2 + i * 132 + c8);
    }
    // lanes L and L+32 share column i -> one xor-32 add, lanes 0..31 store
    l_part += __shfl_xor(l_part, 32, 64);
    if (lane < 32)
        lbuf[((size_t)(js * 128 + bi)) * 128 + w * 32 + il] = l_part;
}

// ---------------- Kernel 4: merge 4 partials + MFMA out-proj + residual --------
// 512 blocks = (b, iblk, quarter of 32 pos). Fixed softmax shift -> merge is
// just (sum of partials) * 1/(sum of l). partO [i][c]: coalesced row reads.
__global__ __launch_bounds__(256, 2) void merge_out(
        const u16* __restrict__ partO, const float* __restrict__ lbuf,
        const u16* __restrict__ wo, const float* __restrict__ b_out,
        const float* __restrict__ x, float* __restrict__ out) {
    __shared__ __align__(16) u16 h2T[32 * 136];
    __shared__ float fac[32];
    int bx = blockIdx.x;           // 512
    int qtr = bx & 3, iblk = (bx >> 2) & 31, b = bx >> 7;
    int bi = b * 32 + iblk;
    int i_base = qtr * 32;
    int t = threadIdx.x, w = t >> 6, lane = t & 63;
    int quad = lane >> 4, l15 = lane & 15;

    short8 wf[2][4];
    #pragma unroll
    for (int j = 0; j < 2; ++j)
        #pragma unroll
        for (int kt = 0; kt < 4; ++kt)
            wf[j][kt] = *(const short8*)(wo + ((w * 2 + j) * 16 + l15) * 128 + kt * 32 + quad * 8);

    if (t < 32) {
        int i = i_base + t;
        float lv = 0.f;
        #pragma unroll
        for (int s = 0; s < 4; ++s)
            lv += lbuf[((size_t)(s * 128 + bi)) * 128 + i];
        fac[t] = 1.f / lv;
    }
    __syncthreads();

    // merge: thread -> (il = t>>3 in 0..31, oct = t&7 -> 16-c strip)
    {
        int il = t >> 3, oct = t & 7;
        int i = i_base + il;
        float accv[16];
        #pragma unroll
        for (int e = 0; e < 16; ++e) accv[e] = 0.f;
        for (int s = 0; s < 4; ++s) {
            const u16* pb = partO + ((size_t)(s * 128 + bi)) * 16384
                            + i * 128 + oct * 16;
            uint4 lo = *(const uint4*)(pb);
            uint4 hi = *(const uint4*)(pb + 8);
            accv[0]  += lo16(lo.x); accv[1]  += hi16(lo.x);
            accv[2]  += lo16(lo.y); accv[3]  += hi16(lo.y);
            accv[4]  += lo16(lo.z); accv[5]  += hi16(lo.z);
            accv[6]  += lo16(lo.w); accv[7]  += hi16(lo.w);
            accv[8]  += lo16(hi.x); accv[9]  += hi16(hi.x);
            accv[10] += lo16(hi.y); accv[11] += hi16(hi.y);
            accv[12] += lo16(hi.z); accv[13] += hi16(hi.z);
            accv[14] += lo16(hi.w); accv[15] += hi16(hi.w);
        }
        float fs = fac[il];
        #pragma unroll
        for (int e = 0; e < 16; ++e) accv[e] *= fs;
        uint4 lo = make_uint4(pkbf(accv[0],  accv[1]),  pkbf(accv[2],  accv[3]),
                              pkbf(accv[4],  accv[5]),  pkbf(accv[6],  accv[7]));
        uint4 hi = make_uint4(pkbf(accv[8],  accv[9]),  pkbf(accv[10], accv[11]),
                              pkbf(accv[12], accv[13]), pkbf(accv[14], accv[15]));
        *(uint4*)(h2T + il * 136 + oct * 16)     = lo;
        *(uint4*)(h2T + il * 136 + oct * 16 + 8) = hi;
    }
    __syncthreads();

    floatx4 acc[2][2];
    #pragma unroll
    for (int j = 0; j < 2; ++j) { acc[j][0] = (floatx4)0.f; acc[j][1] = (floatx4)0.f; }
    #pragma unroll
    for (int nt = 0; nt < 2; ++nt)
        #pragma unroll
        for (int kt = 0; kt < 4; ++kt) {
            short8 hf = *(const short8*)(h2T + (nt * 16 + l15) * 136 + kt * 32 + quad * 8);
            acc[0][nt] = mfma16(wf[0][kt], hf, acc[0][nt]);
            acc[1][nt] = mfma16(wf[1][kt], hf, acc[1][nt]);
        }

    int n_base = iblk * 128 + i_base;
    #pragma unroll
    for (int j = 0; j < 2; ++j)
        #pragma unroll
        for (int r = 0; r < 4; ++r) {
            int o = w * 32 + j * 16 + quad * 4 + r;
            float bo = b_out[o];
            #pragma unroll
            for (int nt = 0; nt < 2; ++nt) {
                int n = n_base + nt * 16 + l15;
                size_t idx = ((size_t)(b * 128 + o)) * SEQ + n;
                out[idx] = acc[j][nt][r] + bo + x[idx];
            }
        }
}

// ---------------- launch -------------------------------------------------------
extern "C" void kernel_launch(void* const* d_in, const int* in_sizes, int n_in,
                              void* d_out, int out_size, void* d_ws, size_t ws_size,
                              hipStream_t stream) {
    const float* x     = (const float*)d_in[0];
    const float* gn_w  = (const float*)d_in[1];
    const float* gn_b  = (const float*)d_in[2];
    const float* w_qkv = (const float*)d_in[3];
    const float* b_qkv = (const float*)d_in[4];
    const float* w_out = (const float*)d_in[5];
    const float* b_out = (const float*)d_in[6];
    float* out = (float*)d_out;

    char* ws = (char*)d_ws;
    float* part = (float*)ws;                  //   2 KB @ 0
    u16*  wq  = (u16*)(ws + 4096);             //  96 KB
    u16*  wo  = (u16*)(ws + 102400);           //  32 KB
    u16*  qT  = (u16*)(ws + 135168);           //   4 MB [b][n][c]
    u16*  kT  = (u16*)(ws + 4329472);          //   4 MB [b][n][c]
    u16*  v   = (u16*)(ws + 8523776);          //   4 MB [b][c][n]
    u16*  pO  = (u16*)(ws + 12718080);         //  16 MB partials [js][bi][i][c]
    float* lb = (float*)(ws + 29495296);       // 256 KB
    // total ~29.8 MB

    gn_wconv<<<512, 256, 0, stream>>>(x, part, w_qkv, w_out, wq, wo);
    qkv_fused<<<512, 256, 0, stream>>>(x, gn_w, gn_b, part, wq, b_qkv, qT, kT, v);
    flash_attn<<<512, 256, 0, stream>>>(qT, kT, v, pO, lb);
    merge_out<<<512, 256, 0, stream>>>(pO, lb, wo, b_out, x, out);
}

// Round 15
// 69.106 us; speedup vs baseline: 1.0201x; 1.0201x over previous
//
#include <hip/hip_runtime.h>
#include <hip/hip_bf16.h>

// AttentionBlock B=4, C=128, N=4096.  FINAL (session-converged) state = r5/r13.
// gn_wconv (partial stats + w->bf16)
// -> qkv_fused (GN finalize+apply + MFMA QKV; LDS-restaged coalesced stores)
// -> flash_attn (32x32x16 MFMA, register-resident P via cvt_pk+permlane32_swap;
//                fixed-max softmax (SMAX folded into MFMA acc init); staggered
//                prefetch: K(ch+1) at loop top (held 16 VGPR), V(ch+1) after
//                softmax (transient); sequential jt tiles (one floatx16 acc
//                live); dbuf K/V 71680 B LDS; ONE barrier/chunk; 108 VGPR +
//                64 AGPR = the no-spill edge at 2 blocks/CU.
//                Closed levers: occupancy (r7-r10: 3 waves/SIMD needs <=170
//                total regs, body ~190 -> spills), V-from-global (r6: 32B
//                scatter), T15 pipeline (r12: held regs -> spill), dual-chain
//                QK ILP (r14: null -- compiler already interleaves jt0 softmax
//                with jt1 chain).)
// -> merge_out (sum 4 partials * 1/l + MFMA out-proj + bias + residual)

#define CH 128
#define SEQ 4096
#define EPSV 1e-5f
// 1/sqrt(128) * log2(e): softmax runs in base-2 domain
#define QSCALE (0.08838834764831845f * 1.4426950408889634f)
// fixed softmax shift: base-2 logits bounded |s2| <~ 15; exp2 only overflows
// at s2-M > 127 -> enormous margin. Same M for all j-splits makes merge
// factors collapse to 1/sum(l).
#define SMAX 24.0f

typedef unsigned short u16;
typedef unsigned int u32;
typedef __attribute__((ext_vector_type(8))) short short8;    // 8 bf16 (4 VGPRs)
typedef __attribute__((ext_vector_type(4))) u32 u32x4;
typedef __attribute__((ext_vector_type(4))) float floatx4;   // 16x16 MFMA C/D
typedef __attribute__((ext_vector_type(16))) float floatx16; // 32x32 MFMA C/D

__device__ __forceinline__ float bf2f(u16 h) {
    return __uint_as_float(((u32)h) << 16);
}
__device__ __forceinline__ float lo16(u32 wd) { return __uint_as_float(wd << 16); }
__device__ __forceinline__ float hi16(u32 wd) { return __uint_as_float(wd & 0xffff0000u); }
__device__ __forceinline__ u16 f2bf(float f) {
    u32 u = __float_as_uint(f);
    return (u16)((u + 0x7fffu + ((u >> 16) & 1u)) >> 16);
}
__device__ __forceinline__ u32 pkbf(float a, float b) {   // packed RNE cvt (low=a)
    __hip_bfloat162 h = __float22bfloat162_rn(make_float2(a, b));
    u32 r;
    __builtin_memcpy(&r, &h, 4);   // folds to SSA extract; no alloca
    return r;
}
__device__ __forceinline__ floatx4 mfma16(short8 a, short8 b, floatx4 c) {
    return __builtin_amdgcn_mfma_f32_16x16x32_bf16(a, b, c, 0, 0, 0);
}
__device__ __forceinline__ floatx16 mfma32(short8 a, short8 b, floatx16 c) {
    return __builtin_amdgcn_mfma_f32_32x32x16_bf16(a, b, c, 0, 0, 0);
}
// v_permlane32_swap_b32: a' = [a.lo32, b.lo32], b' = [a.hi32, b.hi32]
// non-volatile: pure lane shuffle, let the scheduler move it freely
__device__ __forceinline__ void pl32(u32& a, u32& b) {
    asm("v_permlane32_swap_b32 %0, %1" : "+v"(a), "+v"(b));
}
__device__ __forceinline__ short8 mk8(u32 a, u32 b, u32 c, u32 d) {
    u32x4 v = (u32x4){a, b, c, d};                        // SSA vector literal
    return __builtin_bit_cast(short8, v);                 // ext_vec -> ext_vec ok
}

// ---------------- Kernel 1: GN partial stats + weight conversion ---------------
// 512 blocks: 0..255 stats (bg,sub), 256..511 weight bf16 convert.
__global__ void gn_wconv(const float* __restrict__ x, float* __restrict__ part,
                         const float* __restrict__ w_qkv, const float* __restrict__ w_out,
                         u16* __restrict__ wq, u16* __restrict__ wo) {
    if (blockIdx.x >= 256) {
        int i = (blockIdx.x - 256) * 256 + threadIdx.x;   // 65536 total
        if (i < 49152) wq[i] = f2bf(w_qkv[i]);
        else           wo[i - 49152] = f2bf(w_out[i - 49152]);
        return;
    }
    int bg = blockIdx.x >> 3, sub = blockIdx.x & 7;
    const float4* xp = (const float4*)(x + (size_t)bg * 65536 + sub * 8192);
    float s = 0.f, sq = 0.f;
    for (int r = 0; r < 8; ++r) {
        float4 v = xp[threadIdx.x + 256 * r];
        s  += v.x + v.y + v.z + v.w;
        sq += v.x*v.x + v.y*v.y + v.z*v.z + v.w*v.w;
    }
    for (int off = 32; off; off >>= 1) {
        s  += __shfl_down(s, off, 64);
        sq += __shfl_down(sq, off, 64);
    }
    __shared__ float ls[8];
    int wave = threadIdx.x >> 6, lane = threadIdx.x & 63;
    if (lane == 0) { ls[wave*2] = s; ls[wave*2+1] = sq; }
    __syncthreads();
    if (threadIdx.x == 0) {
        float ts = 0.f, tq = 0.f;
        for (int w = 0; w < 4; ++w) { ts += ls[w*2]; tq += ls[w*2+1]; }
        part[blockIdx.x * 2]     = ts;
        part[blockIdx.x * 2 + 1] = tq;
    }
}

// ---------------- Kernel 2: fused GN-apply + MFMA QKV projection ---------------
// 512 blocks = (b, 32-pos chunk). hT[32n][136c] in LDS; wave owns 6 o-tiles.
// Epilogue: C tiles -> LDS stage buffers -> fully-coalesced uint4 stores.
__global__ __launch_bounds__(256, 2) void qkv_fused(
        const float* __restrict__ x, const float* __restrict__ gw,
        const float* __restrict__ gb, const float* __restrict__ part,
        const u16* __restrict__ wq, const float* __restrict__ b_qkv,
        u16* __restrict__ qT, u16* __restrict__ kT, u16* __restrict__ v) {
    __shared__ __align__(16) u16 hT[32 * 136];     // input stage
    __shared__ __align__(16) u16 qbuf[32 * 132];   // [n][c] padded
    __shared__ __align__(16) u16 kbuf[32 * 132];
    __shared__ __align__(16) u16 vbuf[128 * 36];   // [c][n] padded
    __shared__ float cw[128], cb[128];
    int bx = blockIdx.x;            // 512
    int nc = bx & 127, b = bx >> 7;
    int n0 = nc * 32;
    int t = threadIdx.x, w = t >> 6, lane = t & 63;
    int quad = lane >> 4, l15 = lane & 15;

    // finalize GN stats -> per-channel scale/bias
    if (t < 128) {
        int g = t >> 4;
        float s = 0.f, sq = 0.f;
        #pragma unroll
        for (int u = 0; u < 8; ++u) {
            s  += part[((b * 8 + g) * 8 + u) * 2];
            sq += part[((b * 8 + g) * 8 + u) * 2 + 1];
        }
        float mean = s / 65536.f;
        float rstd = rsqrtf(sq / 65536.f - mean * mean + EPSV);
        float wgt = gw[t] * rstd;
        cw[t] = wgt;
        cb[t] = gb[t] - mean * wgt;
    }

    // weight fragments: wave w -> o-tiles w*6 .. w*6+5
    short8 wf[6][4];
    float bqk[6];
    #pragma unroll
    for (int j = 0; j < 6; ++j) {
        int orow = (w * 6 + j) * 16 + l15;
        #pragma unroll
        for (int kt = 0; kt < 4; ++kt)
            wf[j][kt] = *(const short8*)(wq + orow * 128 + kt * 32 + quad * 8);
        bqk[j] = b_qkv[orow];
    }
    __syncthreads();

    // stage GN'd x transposed (32 pos x 128 c)
    #pragma unroll
    for (int r = 0; r < 4; ++r) {
        int u = r * 256 + t;
        int c = u >> 3, col = (u & 7) * 4;
        float wgt = cw[c], bs = cb[c];
        float4 xv = *(const float4*)(x + ((size_t)(b * 128 + c)) * SEQ + n0 + col);
        hT[(col + 0) * 136 + c] = f2bf(fmaf(xv.x, wgt, bs));
        hT[(col + 1) * 136 + c] = f2bf(fmaf(xv.y, wgt, bs));
        hT[(col + 2) * 136 + c] = f2bf(fmaf(xv.z, wgt, bs));
        hT[(col + 3) * 136 + c] = f2bf(fmaf(xv.w, wgt, bs));
    }
    __syncthreads();

    #pragma unroll
    for (int nt = 0; nt < 2; ++nt) {
        short8 hf[4];
        #pragma unroll
        for (int kt = 0; kt < 4; ++kt)
            hf[kt] = *(const short8*)(hT + (nt * 16 + l15) * 136 + kt * 32 + quad * 8);
        floatx4 acc[6];
        #pragma unroll
        for (int j = 0; j < 6; ++j) acc[j] = (floatx4)0.f;
        #pragma unroll
        for (int kt = 0; kt < 4; ++kt)
            #pragma unroll
            for (int j = 0; j < 6; ++j) {
                if (w * 6 + j < 16) acc[j] = mfma16(hf[kt], wf[j][kt], acc[j]);
                else                acc[j] = mfma16(wf[j][kt], hf[kt], acc[j]);
            }
        // scatter C tiles into LDS stage buffers
        #pragma unroll
        for (int j = 0; j < 6; ++j) {
            int T = w * 6 + j;
            if (T < 8) {            // q: C[pos][o] -> qbuf[n][c]
                int o = T * 16 + l15;
                #pragma unroll
                for (int r = 0; r < 4; ++r)
                    qbuf[(nt * 16 + quad * 4 + r) * 132 + o] =
                        f2bf((acc[j][r] + bqk[j]) * QSCALE);
            } else if (T < 16) {    // k -> kbuf[n][c]
                int o = (T - 8) * 16 + l15;
                #pragma unroll
                for (int r = 0; r < 4; ++r)
                    kbuf[(nt * 16 + quad * 4 + r) * 132 + o] =
                        f2bf(acc[j][r] + bqk[j]);
            } else {                // v: C[o][pos] -> vbuf[c][n]
                #pragma unroll
                for (int r = 0; r < 4; ++r) {
                    int ov = (T - 16) * 16 + quad * 4 + r;
                    vbuf[ov * 36 + nt * 16 + l15] = f2bf(acc[j][r] + b_qkv[256 + ov]);
                }
            }
        }
    }
    __syncthreads();

    // cooperative coalesced stores
    {   // q,k: [32n][128c] -> contiguous 4096-elem global region each
        u16* qg = qT + ((size_t)b * SEQ + n0) * CH;
        u16* kg = kT + ((size_t)b * SEQ + n0) * CH;
        #pragma unroll
        for (int rep = 0; rep < 2; ++rep) {
            int idx = rep * 256 + t;
            int n = idx >> 4, c8 = (idx & 15) * 8;
            *(uint4*)(qg + n * CH + c8) = *(const uint4*)(qbuf + n * 132 + c8);
            *(uint4*)(kg + n * CH + c8) = *(const uint4*)(kbuf + n * 132 + c8);
        }
        // v: [128c][32n] -> per-c rows of 64 B
        #pragma unroll
        for (int rep = 0; rep < 2; ++rep) {
            int idx = rep * 256 + t;
            int c = idx >> 2, n8 = (idx & 3) * 8;
            *(uint4*)(v + ((size_t)(b * CH + c)) * SEQ + n0 + n8) =
                *(const uint4*)(vbuf + c * 36 + n8);
        }
    }
}

// ---------------- Kernel 3: MFMA flash attention (32x32, register P) -----------
// 512 blocks = (b, iblk of 128 i, js of 4); 16 chunks of 64 j per split.
// js-fastest ordering (per-XCD WS fits L2). 4 waves x 32-i tiles.
// S^T (A=K, B=Q) via 32x32x16 MFMA; SMAX folded into acc init; P -> PV
// B-frags fully in-register (cvt_pk + permlane32_swap).
// Staggered prefetch (spill control): K(ch+1) issued at loop top (held
// 16 VGPRs, hidden under whole body); V(ch+1) issued after softmax
// (transient 16 VGPRs, hidden under PV); both ds-written at iter end.
// Sequential jt tiles: ONE floatx16 score acc live at a time. 108 VGPR.
// Double-buffered K/V (71680 B LDS, 0 bank conflicts), ONE barrier per chunk.
__global__ __launch_bounds__(256, 2) void flash_attn(
        const u16* __restrict__ qT, const u16* __restrict__ kT,
        const u16* __restrict__ v, u16* __restrict__ partO,
        float* __restrict__ lbuf) {
    __shared__ __align__(16) char smem[71680];
    // buffer p (p=0,1): kts = smem + p*35840 [64 j][136 c] (17408 B),
    //                   vts = kts + 17408   [128 c][72 j]  (18432 B)
    u16* qts = (u16*)(smem + 35840);   // [128 i][136 c] aliases buffer 1 (init)
    u16* lds2 = (u16*)smem;            // [128 i][132 c] epilogue restage (buf 0)

    int bx = blockIdx.x;               // js fastest -> L2/XCD locality
    int js = bx & 3, iblk = (bx >> 2) & 31, b = bx >> 7;
    int t = threadIdx.x, w = t >> 6, lane = t & 63;
    int il = lane & 31, h = lane >> 5;
    int i0 = iblk * 128, j0 = js * 1024;

    // per-thread staging coordinates
    int tj = t >> 4, tc8 = (t & 15) * 8;    // K: j = r*16+tj, c-offset tc8
    int tv = t >> 3, vc8 = (t & 7) * 8;     // V: c = r*32+tv, j-offset vc8

    // ---- stage Q tile ([n][c]) into buffer-1 region, read 32x32 B-frags ----
    {
        const u16* qb = qT + ((size_t)b * SEQ + i0) * CH;
        for (int r = 0; r < 8; ++r) {
            int u = r * 256 + t;
            int i = u >> 4, c16 = u & 15;
            *(uint4*)(qts + i * 136 + c16 * 8) =
                *(const uint4*)(qb + (size_t)i * CH + c16 * 8);
        }
    }
    __syncthreads();
    short8 qf[8];   // B[k=c][n=i]: lane holds Q[i = w*32+il][c = kc*16 + 8h + e]
    #pragma unroll
    for (int kc = 0; kc < 8; ++kc)
        qf[kc] = *(const short8*)(qts + (w * 32 + il) * 136 + kc * 16 + h * 8);
    // qts (buffer 1) is first overwritten by the ds_write at the END of iter 0
    // (staging chunk 1), which is past the prologue barrier below -> all waves'
    // qf ds_reads complete (own-wave lgkmcnt + barrier ordering) before that.

    const u16* kTb = kT + ((size_t)b * SEQ + j0) * CH;
    const u16* vb  = v  + (size_t)b * CH * SEQ + j0;

    // ---- prologue: stage chunk 0 into buffer 0 (transient regs) ----
    {
        u16* kts0 = (u16*)smem;
        u16* vts0 = kts0 + 8704;
        #pragma unroll
        for (int r = 0; r < 4; ++r)
            *(uint4*)(kts0 + (r * 16 + tj) * 136 + tc8) =
                *(const uint4*)(kTb + (size_t)(r * 16 + tj) * CH + tc8);
        #pragma unroll
        for (int r = 0; r < 4; ++r)
            *(uint4*)(vts0 + (r * 32 + tv) * 72 + vc8) =
                *(const uint4*)(vb + (size_t)(r * 32 + tv) * SEQ + vc8);
    }
    __syncthreads();

    float l_part = 0.f;
    floatx16 o[4];   // O^T[c = ct*32+row][i = il]
    #pragma unroll
    for (int ct = 0; ct < 4; ++ct) o[ct] = (floatx16)0.f;

    for (int ch = 0; ch < 16; ++ch) {
        u16* kts = (u16*)(smem + (ch & 1) * 35840);
        u16* vts = kts + 8704;   // +17408 B
        u16* ktsN = (u16*)(smem + ((ch + 1) & 1) * 35840);
        u16* vtsN = ktsN + 8704;
        int jb1 = (ch + 1) * 64;
        bool pf = (ch < 15);

        // K(ch+1) global loads: issued first, consumed at iter end (ds_write).
        // Latency hidden under the entire chunk body.
        uint4 kreg[4];
        if (pf) {
            #pragma unroll
            for (int r = 0; r < 4; ++r)
                kreg[r] = *(const uint4*)(kTb + (size_t)(jb1 + r * 16 + tj) * CH + tc8);
        }

        // ---- QK + softmax + pack, one 32-j tile at a time (reg pressure) ----
        // S^T tile: row j_loc = jt*32 + (r&3)+8*(r>>2)+4h, col i = il.
        // acc init at -SMAX => scores come out pre-shifted. The compiler
        // interleaves tile-1's MFMA chain with tile-0's softmax VALU.
        short8 pfr[4];   // PV B-frags: j 0..15 / 16..31 / 32..47 / 48..63
        #pragma unroll
        for (int jt = 0; jt < 2; ++jt) {
            floatx16 s = (floatx16)(-SMAX);
            #pragma unroll
            for (int kc = 0; kc < 8; ++kc) {
                short8 kf = *(const short8*)(kts + (jt * 32 + il) * 136 + kc * 16 + h * 8);
                s = mfma32(kf, qf[kc], s);
            }
            float p[16];
            #pragma unroll
            for (int r = 0; r < 16; ++r) p[r] = __builtin_amdgcn_exp2f(s[r]);
            l_part += ((((p[0]+p[1])+(p[2]+p[3])) + ((p[4]+p[5])+(p[6]+p[7])))
                    +  (((p[8]+p[9])+(p[10]+p[11])) + ((p[12]+p[13])+(p[14]+p[15]))));
            u32 a0 = pkbf(p[0],  p[1]),  a1 = pkbf(p[2],  p[3]);
            u32 a2 = pkbf(p[4],  p[5]),  a3 = pkbf(p[6],  p[7]);
            u32 b0 = pkbf(p[8],  p[9]),  b1 = pkbf(p[10], p[11]);
            u32 b2 = pkbf(p[12], p[13]), b3 = pkbf(p[14], p[15]);
            pl32(a0, a2); pl32(a1, a3);
            pl32(b0, b2); pl32(b1, b3);
            pfr[2 * jt]     = mk8(a0, a1, a2, a3);
            pfr[2 * jt + 1] = mk8(b0, b1, b2, b3);
        }

        // V(ch+1) global loads: issued after softmax, consumed at iter end.
        // Latency hidden under PV. Transient 16 VGPRs.
        uint4 vreg[4];
        if (pf) {
            #pragma unroll
            for (int r = 0; r < 4; ++r)
                vreg[r] = *(const uint4*)(vb + (size_t)(r * 32 + tv) * SEQ + jb1 + vc8);
        }

        // ---- PV: O^T[c][i] += V[c][j] * P[i][j]^T; 4 indep chains ----
        __builtin_amdgcn_s_setprio(1);
        #pragma unroll
        for (int ct = 0; ct < 4; ++ct) {
            const u16* vrow = vts + (ct * 32 + il) * 72;
            short8 vf0 = *(const short8*)(vrow + h * 8);
            short8 vf1 = *(const short8*)(vrow + 16 + h * 8);
            short8 vf2 = *(const short8*)(vrow + 32 + h * 8);
            short8 vf3 = *(const short8*)(vrow + 48 + h * 8);
            o[ct] = mfma32(vf0, pfr[0], o[ct]);
            o[ct] = mfma32(vf1, pfr[1], o[ct]);
            o[ct] = mfma32(vf2, pfr[2], o[ct]);
            o[ct] = mfma32(vf3, pfr[3], o[ct]);
        }
        __builtin_amdgcn_s_setprio(0);

        // ---- write chunk ch+1 into the other buffer, single barrier ----
        // Safe: all waves passed barrier(ch), so every wave's reads of
        // buf[(ch+1)&1] (done during iter ch-1) are complete.
        if (pf) {
            #pragma unroll
            for (int r = 0; r < 4; ++r)
                *(uint4*)(ktsN + (r * 16 + tj) * 136 + tc8) = kreg[r];
            #pragma unroll
            for (int r = 0; r < 4; ++r)
                *(uint4*)(vtsN + (r * 32 + tv) * 72 + vc8) = vreg[r];
        }
        __syncthreads();
    }

    // ---- epilogue: O tiles -> LDS restage -> fully-coalesced stores ----
    // C layout: col i = il (wave rows w*32+il), row c = ct*32 + (r&3)+8*(r>>2)+4h.
    // lds2 sits in buffer 0: chunk-14 reads of buffer 0 completed before the
    // final barrier at the end of iter 15, so writing here is race-free.
    #pragma unroll
    for (int ct = 0; ct < 4; ++ct)
        #pragma unroll
        for (int g = 0; g < 4; ++g) {
            uint2 pk2 = make_uint2(pkbf(o[ct][4*g+0], o[ct][4*g+1]),
                                   pkbf(o[ct][4*g+2], o[ct][4*g+3]));
            *(uint2*)(lds2 + (w * 32 + il) * 132 + ct * 32 + 8 * g + 4 * h) = pk2;
        }
    __syncthreads();
    int bi = b * 32 + iblk;
    u16* pb = partO + ((size_t)(js * 128 + bi)) * 16384;   // [128 i][128 c]
    #pragma unroll
    for (int rep = 0; rep < 8; ++rep) {
        int idx = rep * 256 + t;
        int i = idx >> 4, c8 = (idx & 15) * 8;
        *(uint4*)(pb + i * 128 + c8) = *(const uint4*)(lds2 + i * 132 + c8);
    }
    // lanes L and L+32 share column i -> one xor-32 add, lanes 0..31 store
    l_part += __shfl_xor(l_part, 32, 64);
    if (lane < 32)
        lbuf[((size_t)(js * 128 + bi)) * 128 + w * 32 + il] = l_part;
}

// ---------------- Kernel 4: merge 4 partials + MFMA out-proj + residual --------
// 512 blocks = (b, iblk, quarter of 32 pos). Fixed softmax shift -> merge is
// just (sum of partials) * 1/(sum of l). partO [i][c]: coalesced row reads.
__global__ __launch_bounds__(256, 2) void merge_out(
        const u16* __restrict__ partO, const float* __restrict__ lbuf,
        const u16* __restrict__ wo, const float* __restrict__ b_out,
        const float* __restrict__ x, float* __restrict__ out) {
    __shared__ __align__(16) u16 h2T[32 * 136];
    __shared__ float fac[32];
    int bx = blockIdx.x;           // 512
    int qtr = bx & 3, iblk = (bx >> 2) & 31, b = bx >> 7;
    int bi = b * 32 + iblk;
    int i_base = qtr * 32;
    int t = threadIdx.x, w = t >> 6, lane = t & 63;
    int quad = lane >> 4, l15 = lane & 15;

    short8 wf[2][4];
    #pragma unroll
    for (int j = 0; j < 2; ++j)
        #pragma unroll
        for (int kt = 0; kt < 4; ++kt)
            wf[j][kt] = *(const short8*)(wo + ((w * 2 + j) * 16 + l15) * 128 + kt * 32 + quad * 8);

    if (t < 32) {
        int i = i_base + t;
        float lv = 0.f;
        #pragma unroll
        for (int s = 0; s < 4; ++s)
            lv += lbuf[((size_t)(s * 128 + bi)) * 128 + i];
        fac[t] = 1.f / lv;
    }
    __syncthreads();

    // merge: thread -> (il = t>>3 in 0..31, oct = t&7 -> 16-c strip)
    {
        int il = t >> 3, oct = t & 7;
        int i = i_base + il;
        float accv[16];
        #pragma unroll
        for (int e = 0; e < 16; ++e) accv[e] = 0.f;
        for (int s = 0; s < 4; ++s) {
            const u16* pb = partO + ((size_t)(s * 128 + bi)) * 16384
                            + i * 128 + oct * 16;
            uint4 lo = *(const uint4*)(pb);
            uint4 hi = *(const uint4*)(pb + 8);
            accv[0]  += lo16(lo.x); accv[1]  += hi16(lo.x);
            accv[2]  += lo16(lo.y); accv[3]  += hi16(lo.y);
            accv[4]  += lo16(lo.z); accv[5]  += hi16(lo.z);
            accv[6]  += lo16(lo.w); accv[7]  += hi16(lo.w);
            accv[8]  += lo16(hi.x); accv[9]  += hi16(hi.x);
            accv[10] += lo16(hi.y); accv[11] += hi16(hi.y);
            accv[12] += lo16(hi.z); accv[13] += hi16(hi.z);
            accv[14] += lo16(hi.w); accv[15] += hi16(hi.w);
        }
        float fs = fac[il];
        #pragma unroll
        for (int e = 0; e < 16; ++e) accv[e] *= fs;
        uint4 lo = make_uint4(pkbf(accv[0],  accv[1]),  pkbf(accv[2],  accv[3]),
                              pkbf(accv[4],  accv[5]),  pkbf(accv[6],  accv[7]));
        uint4 hi = make_uint4(pkbf(accv[8],  accv[9]),  pkbf(accv[10], accv[11]),
                              pkbf(accv[12], accv[13]), pkbf(accv[14], accv[15]));
        *(uint4*)(h2T + il * 136 + oct * 16)     = lo;
        *(uint4*)(h2T + il * 136 + oct * 16 + 8) = hi;
    }
    __syncthreads();

    floatx4 acc[2][2];
    #pragma unroll
    for (int j = 0; j < 2; ++j) { acc[j][0] = (floatx4)0.f; acc[j][1] = (floatx4)0.f; }
    #pragma unroll
    for (int nt = 0; nt < 2; ++nt)
        #pragma unroll
        for (int kt = 0; kt < 4; ++kt) {
            short8 hf = *(const short8*)(h2T + (nt * 16 + l15) * 136 + kt * 32 + quad * 8);
            acc[0][nt] = mfma16(wf[0][kt], hf, acc[0][nt]);
            acc[1][nt] = mfma16(wf[1][kt], hf, acc[1][nt]);
        }

    int n_base = iblk * 128 + i_base;
    #pragma unroll
    for (int j = 0; j < 2; ++j)
        #pragma unroll
        for (int r = 0; r < 4; ++r) {
            int o = w * 32 + j * 16 + quad * 4 + r;
            float bo = b_out[o];
            #pragma unroll
            for (int nt = 0; nt < 2; ++nt) {
                int n = n_base + nt * 16 + l15;
                size_t idx = ((size_t)(b * 128 + o)) * SEQ + n;
                out[idx] = acc[j][nt][r] + bo + x[idx];
            }
        }
}

// ---------------- launch -------------------------------------------------------
extern "C" void kernel_launch(void* const* d_in, const int* in_sizes, int n_in,
                              void* d_out, int out_size, void* d_ws, size_t ws_size,
                              hipStream_t stream) {
    const float* x     = (const float*)d_in[0];
    const float* gn_w  = (const float*)d_in[1];
    const float* gn_b  = (const float*)d_in[2];
    const float* w_qkv = (const float*)d_in[3];
    const float* b_qkv = (const float*)d_in[4];
    const float* w_out = (const float*)d_in[5];
    const float* b_out = (const float*)d_in[6];
    float* out = (float*)d_out;

    char* ws = (char*)d_ws;
    float* part = (float*)ws;                  //   2 KB @ 0
    u16*  wq  = (u16*)(ws + 4096);             //  96 KB
    u16*  wo  = (u16*)(ws + 102400);           //  32 KB
    u16*  qT  = (u16*)(ws + 135168);           //   4 MB [b][n][c]
    u16*  kT  = (u16*)(ws + 4329472);          //   4 MB [b][n][c]
    u16*  v   = (u16*)(ws + 8523776);          //   4 MB [b][c][n]
    u16*  pO  = (u16*)(ws + 12718080);         //  16 MB partials [js][bi][i][c]
    float* lb = (float*)(ws + 29495296);       // 256 KB
    // total ~29.8 MB

    gn_wconv<<<512, 256, 0, stream>>>(x, part, w_qkv, w_out, wq, wo);
    qkv_fused<<<512, 256, 0, stream>>>(x, gn_w, gn_b, part, wq, b_qkv, qT, kT, v);
    flash_attn<<<512, 256, 0, stream>>>(qT, kT, v, pO, lb);
    merge_out<<<512, 256, 0, stream>>>(pO, lb, wo, b_out, x, out);
}